// Round 4
// baseline (413.625 us; speedup 1.0000x reference)
//
#include <hip/hip_runtime.h>
#include <cmath>

#define B_ 32
#define N_ 197
#define C_ 768
#define H_ 12
#define D_ 64
#define M_ (B_*N_)        // 6304
#define MPAD_ 6400        // padded rows for 128-tiles
#define K3_ (3*C_)        // 2304
#define NN_ (N_*N_)       // 38809
#define BH_ (B_*H_)       // 384
#define NP_ 208           // 13*16 row pad
#define KP_ 224           // 7*32 k pad for av (aw row stride)
#define VTS_ 256          // vT row stride (pow2 for swizzle bijectivity)
#define SCALE 0.125f

typedef __bf16 bf16x8 __attribute__((ext_vector_type(8)));
typedef __bf16 bf16x4 __attribute__((ext_vector_type(4)));
typedef float  f32x4  __attribute__((ext_vector_type(4)));
// 4-byte-aligned float4 for stores at (row*197 + m)*4B addresses (not 16B aligned)
typedef float  f32x4u __attribute__((ext_vector_type(4), aligned(4)));

__device__ __forceinline__ void gl_lds16(const void* g, void* l) {
    __builtin_amdgcn_global_load_lds(
        (const __attribute__((address_space(1))) void*)g,
        (__attribute__((address_space(3))) void*)l,
        16, 0, 0);
}

// ---------------------------------------------------------------------------
// prep: merged cast_x + transpose_cast(w_qkv) + transpose_cast(w_proj) + zero vT.
__device__ __forceinline__ void transpose_tile(const float* __restrict__ W,
        __bf16* __restrict__ Wt, int R, int Ccols, int c0, int r0,
        float (*t)[33], int tid) {
    const int tx = tid & 31, ty = tid >> 5;
    #pragma unroll
    for (int i = ty; i < 32; i += 8)
        t[i][tx] = W[(size_t)(r0 + i) * Ccols + c0 + tx];
    __syncthreads();
    #pragma unroll
    for (int i = ty; i < 32; i += 8)
        Wt[(size_t)(c0 + i) * R + r0 + tx] = (__bf16)t[tx][i];
}

__global__ __launch_bounds__(256) void prep_kernel(const float* __restrict__ X,
        __bf16* __restrict__ Xb, const float* __restrict__ Wq,
        __bf16* __restrict__ Wqt, const float* __restrict__ Wp,
        __bf16* __restrict__ Wpt, __bf16* __restrict__ vT) {
    __shared__ float t[32][33];
    const int bid = blockIdx.x, tid = threadIdx.x;
    if (bid < 4800) {
        const long long i = ((long long)bid * 256 + tid) * 4;
        bf16x4 o;
        if (i < (long long)M_ * 768) {
            float4 f = *(const float4*)&X[i];
            o.x = (__bf16)f.x; o.y = (__bf16)f.y; o.z = (__bf16)f.z; o.w = (__bf16)f.w;
        } else {
            o.x = o.y = o.z = o.w = (__bf16)0.f;
        }
        *(bf16x4*)&Xb[i] = o;
    } else if (bid < 6528) {
        const int tt = bid - 4800;
        transpose_tile(Wq, Wqt, 768, K3_, (tt % 72) * 32, (tt / 72) * 32, t, tid);
    } else if (bid < 7104) {
        const int tt = bid - 6528;
        transpose_tile(Wp, Wpt, 768, 768, (tt % 24) * 32, (tt / 24) * 32, t, tid);
    } else {
        // zero vT [BH_][64][VTS_]: 384*64*256 elems / 8 per thread = 786432 chunks
        const size_t idx = ((size_t)(bid - 7104) * 256 + tid) * 8;
        bf16x8 z = {};
        *(bf16x8*)&vT[idx] = z;
    }
}

// ---------------------------------------------------------------------------
// MFMA GEMM: Xb[M,768] @ Wt[2304,768]^T -> scatter to q,k,v BF16 [B,H,N,D];
// v additionally emitted as swizzled-transposed vT[bh][d][m] (stride VTS_).
__global__ __launch_bounds__(256) void mfma_qkv(const __bf16* __restrict__ Xb,
        const __bf16* __restrict__ Wt, __bf16* __restrict__ q,
        __bf16* __restrict__ k, __bf16* __restrict__ v,
        __bf16* __restrict__ vT) {
    __shared__ __bf16 As[128*32];
    __shared__ __bf16 Bs[128*32];
    const int tid = threadIdx.x;
    const int wv = tid >> 6, ln = tid & 63;
    const int R0 = blockIdx.x * 128;
    const int C0 = blockIdx.y * 128;
    const int wm = wv >> 1, wn = wv & 1;
    const int arow = ln >> 2, akg = ln & 3;
    f32x4 acc[4][4] = {};
    for (int k0 = 0; k0 < 768; k0 += 32) {
        __syncthreads();
        #pragma unroll
        for (int s = 0; s < 2; s++) {
            const int seg = wv + s*4;
            const int row = seg*16 + arow;
            gl_lds16(Xb + (size_t)(R0 + row)*768 + k0 + akg*8,
                     (char*)As + seg*1024 + ln*16);
            gl_lds16(Wt + (size_t)(C0 + row)*768 + k0 + akg*8,
                     (char*)Bs + seg*1024 + ln*16);
        }
        __syncthreads();
        bf16x8 af[4], bfr[4];
        #pragma unroll
        for (int t = 0; t < 4; t++) {
            af[t]  = *(const bf16x8*)((const char*)As +
                        (wm*64 + t*16 + (ln & 15))*64 + (ln >> 4)*16);
            bfr[t] = *(const bf16x8*)((const char*)Bs +
                        (wn*64 + t*16 + (ln & 15))*64 + (ln >> 4)*16);
        }
        #pragma unroll
        for (int i = 0; i < 4; i++)
            #pragma unroll
            for (int j = 0; j < 4; j++)
                acc[i][j] = __builtin_amdgcn_mfma_f32_16x16x32_bf16(
                                af[i], bfr[j], acc[i][j], 0, 0, 0);
    }
    const int lr = (ln >> 4) * 4;
    const int lc = ln & 15;
    #pragma unroll
    for (int j = 0; j < 4; j++) {
        const int c = C0 + wn*64 + j*16 + lc;
        const int which = c / 768;
        const int rem = c - which*768;
        const int h = rem >> 6, d = rem & 63;
        __bf16* dst = (which == 0) ? q : ((which == 1) ? k : v);
        #pragma unroll
        for (int i = 0; i < 4; i++) {
            #pragma unroll
            for (int rr = 0; rr < 4; rr++) {
                const int r = R0 + wm*64 + i*16 + lr + rr;
                if (r < M_) {
                    const int bb = r / N_, n = r - bb*N_;
                    const __bf16 val = (__bf16)acc[i][j][rr];
                    dst[(((size_t)(bb*H_ + h))*N_ + n)*64 + d] = val;
                    if (which == 2) {
                        // swizzled transposed copy for av: slot = (n/8) ^ (d&7)
                        vT[(((size_t)(bb*H_ + h))*64 + d)*VTS_ +
                           ((((n >> 3) ^ (d & 7))) << 3) + (n & 7)] = val;
                    }
                }
            }
        }
    }
}

// ---------------------------------------------------------------------------
// MFMA GEMM: out[M,768] = OPb[M,768] @ Wpt[768,768]^T + bias (fp32 out).
// 128x128 tiles (config of the 383us-verified build).
__global__ __launch_bounds__(256) void mfma_proj(const __bf16* __restrict__ Ab,
        const __bf16* __restrict__ Wt, const float* __restrict__ bias,
        float* __restrict__ Y) {
    __shared__ __bf16 As[128*32];
    __shared__ __bf16 Bs[128*32];
    const int tid = threadIdx.x;
    const int wv = tid >> 6, ln = tid & 63;
    const int R0 = blockIdx.x * 128;
    const int C0 = blockIdx.y * 128;
    const int wm = wv >> 1, wn = wv & 1;
    const int arow = ln >> 2, akg = ln & 3;
    f32x4 acc[4][4] = {};
    for (int k0 = 0; k0 < 768; k0 += 32) {
        __syncthreads();
        #pragma unroll
        for (int s = 0; s < 2; s++) {
            const int seg = wv + s*4;
            const int row = seg*16 + arow;
            gl_lds16(Ab + (size_t)(R0 + row)*768 + k0 + akg*8,
                     (char*)As + seg*1024 + ln*16);
            gl_lds16(Wt + (size_t)(C0 + row)*768 + k0 + akg*8,
                     (char*)Bs + seg*1024 + ln*16);
        }
        __syncthreads();
        bf16x8 af[4], bfr[4];
        #pragma unroll
        for (int t = 0; t < 4; t++) {
            af[t]  = *(const bf16x8*)((const char*)As +
                        (wm*64 + t*16 + (ln & 15))*64 + (ln >> 4)*16);
            bfr[t] = *(const bf16x8*)((const char*)Bs +
                        (wn*64 + t*16 + (ln & 15))*64 + (ln >> 4)*16);
        }
        #pragma unroll
        for (int i = 0; i < 4; i++)
            #pragma unroll
            for (int j = 0; j < 4; j++)
                acc[i][j] = __builtin_amdgcn_mfma_f32_16x16x32_bf16(
                                af[i], bfr[j], acc[i][j], 0, 0, 0);
    }
    const int lr = (ln >> 4) * 4;
    const int lc = ln & 15;
    #pragma unroll
    for (int j = 0; j < 4; j++) {
        const int c = C0 + wn*64 + j*16 + lc;
        const float bv = bias[c];
        #pragma unroll
        for (int i = 0; i < 4; i++) {
            #pragma unroll
            for (int rr = 0; rr < 4; rr++) {
                const int r = R0 + wm*64 + i*16 + lr + rr;
                if (r < M_) Y[(size_t)r*768 + c] = acc[i][j][rr] + bv;
            }
        }
    }
}

// ---------------------------------------------------------------------------
// Fused dual kernel: blocks [0,384) S = SCALE*Q K^T, rest VM = softmax(SCALE*V V^T).
// Swapped MFMA operands (lane owns 4 consecutive m -> float4 stores).
// LDS XOR-swizzled (slot ^= row&7 within 128B rows): fragment reads put 16
// lanes on 16 rows at one 16B column -> was ~16-way bank conflict, now 2-way.
__global__ __launch_bounds__(256) void qkt_vvt(const __bf16* __restrict__ Q,
        const __bf16* __restrict__ Km, const __bf16* __restrict__ V,
        float* __restrict__ S, float* __restrict__ VM) {
    __shared__ __bf16 Al[NP_*64];
    __shared__ __bf16 Bl[NP_*64];
    const int tid = threadIdx.x;
    const int w = tid >> 6, L = tid & 63;
    const int lm = L & 15, lg = L >> 4;
    if (blockIdx.x < BH_) {
        // ----- QK^T path -----
        const int bh = blockIdx.x;
        const __bf16* Qb = Q  + (size_t)bh*N_*D_;
        const __bf16* Kb = Km + (size_t)bh*N_*D_;
        for (int i = tid*8; i < NP_*64; i += 2048) {
            const int row = i >> 6;
            const int c8 = (i >> 3) & 7;
            const int di = (i & ~63) | ((c8 ^ (row & 7)) << 3);
            bf16x8 z = {};
            *(bf16x8*)&Al[di] = (row < N_) ? *(const bf16x8*)&Qb[i] : z;
            *(bf16x8*)&Bl[di] = (row < N_) ? *(const bf16x8*)&Kb[i] : z;
        }
        __syncthreads();
        for (int nt = w; nt < 13; nt += 4) {
            const int qr = nt*16 + lm;
            const bf16x8 q0 = *(const bf16x8*)&Al[qr*64 + ((lg ^ (qr&7)) << 3)];
            const bf16x8 q1 = *(const bf16x8*)&Al[qr*64 + (((4+lg) ^ (qr&7)) << 3)];
            const int n = qr;
            float* Srow = S + ((size_t)bh*N_ + n)*N_;
            for (int mt = 0; mt < 13; mt++) {
                const int kr = mt*16 + lm;
                const bf16x8 k0 = *(const bf16x8*)&Bl[kr*64 + ((lg ^ (kr&7)) << 3)];
                const bf16x8 k1 = *(const bf16x8*)&Bl[kr*64 + (((4+lg) ^ (kr&7)) << 3)];
                f32x4 acc = {};
                acc = __builtin_amdgcn_mfma_f32_16x16x32_bf16(k0, q0, acc, 0, 0, 0);
                acc = __builtin_amdgcn_mfma_f32_16x16x32_bf16(k1, q1, acc, 0, 0, 0);
                if (n < N_) {
                    const int m0 = mt*16 + lg*4;
                    if (m0 + 3 < N_) {
                        f32x4 st;
                        #pragma unroll
                        for (int r = 0; r < 4; r++) st[r] = acc[r] * SCALE;
                        *(f32x4u*)&Srow[m0] = st;
                    } else {
                        #pragma unroll
                        for (int r = 0; r < 4; r++)
                            if (m0 + r < N_) Srow[m0 + r] = acc[r] * SCALE;
                    }
                }
            }
        }
    } else {
        // ----- softmax(V V^T) path -----
        const int bh = blockIdx.x - BH_;
        const __bf16* Vb = V + (size_t)bh*N_*D_;
        for (int i = tid*8; i < NP_*64; i += 2048) {
            const int row = i >> 6;
            const int c8 = (i >> 3) & 7;
            const int di = (i & ~63) | ((c8 ^ (row & 7)) << 3);
            bf16x8 z = {};
            *(bf16x8*)&Al[di] = (row < N_) ? *(const bf16x8*)&Vb[i] : z;
        }
        __syncthreads();
        for (int nt = w; nt < 13; nt += 4) {
            const int qr = nt*16 + lm;
            const bf16x8 q0 = *(const bf16x8*)&Al[qr*64 + ((lg ^ (qr&7)) << 3)];
            const bf16x8 q1 = *(const bf16x8*)&Al[qr*64 + (((4+lg) ^ (qr&7)) << 3)];
            f32x4 acc[13];
            for (int mt = 0; mt < 13; mt++) {
                const int kr = mt*16 + lm;
                const bf16x8 a0 = *(const bf16x8*)&Al[kr*64 + ((lg ^ (kr&7)) << 3)];
                const bf16x8 a1 = *(const bf16x8*)&Al[kr*64 + (((4+lg) ^ (kr&7)) << 3)];
                f32x4 a = {};
                a = __builtin_amdgcn_mfma_f32_16x16x32_bf16(a0, q0, a, 0, 0, 0);
                a = __builtin_amdgcn_mfma_f32_16x16x32_bf16(a1, q1, a, 0, 0, 0);
                acc[mt] = a;
            }
            // scale; mask invalid m in last tile (m = 192 + lg*4 + r)
            #pragma unroll
            for (int mt = 0; mt < 13; mt++)
                #pragma unroll
                for (int r = 0; r < 4; r++) acc[mt][r] *= SCALE;
            #pragma unroll
            for (int r = 0; r < 4; r++)
                if (192 + lg*4 + r >= N_) acc[12][r] = -1e30f;
            float mx = -1e30f;
            #pragma unroll
            for (int mt = 0; mt < 13; mt++)
                #pragma unroll
                for (int r = 0; r < 4; r++) mx = fmaxf(mx, acc[mt][r]);
            mx = fmaxf(mx, __shfl_xor(mx, 16));
            mx = fmaxf(mx, __shfl_xor(mx, 32));
            float sm = 0.f;
            #pragma unroll
            for (int mt = 0; mt < 13; mt++)
                #pragma unroll
                for (int r = 0; r < 4; r++) {
                    const float e = __expf(acc[mt][r] - mx);
                    acc[mt][r] = e;
                    sm += e;
                }
            sm += __shfl_xor(sm, 16);
            sm += __shfl_xor(sm, 32);
            const float inv = 1.f / sm;
            const int n = qr;
            if (n < N_) {
                float* Vrow = VM + ((size_t)bh*N_ + n)*N_;
                #pragma unroll
                for (int mt = 0; mt < 12; mt++) {
                    f32x4 st;
                    #pragma unroll
                    for (int r = 0; r < 4; r++) st[r] = acc[mt][r] * inv;
                    *(f32x4u*)&Vrow[mt*16 + lg*4] = st;
                }
                #pragma unroll
                for (int r = 0; r < 4; r++) {
                    const int m = 192 + lg*4 + r;
                    if (m < N_) Vrow[m] = acc[12][r] * inv;
                }
            }
        }
    }
}

// ---------------------------------------------------------------------------
// Fused probs = softmax(conv_l(scores)), attn_w = conv_w(probs).
// One block per (b, 4-row group). Position-parallel in-place 12x12 mixes.
__global__ __launch_bounds__(256) void convl_convw(const float* __restrict__ SC,
        const float* __restrict__ wl, const float* __restrict__ ww,
        float* __restrict__ PR, __bf16* __restrict__ AW) {
    __shared__ float sbuf[12][4][200];
    __shared__ float wls[144];
    __shared__ float wws[144];
    const int tid = threadIdx.x;
    const int b = blockIdx.x / 50;
    const int n0 = (blockIdx.x - b * 50) * 4;
    if (tid < 144) { wls[tid] = wl[tid]; wws[tid] = ww[tid]; }
    // phase1: scores -> LDS (4 contiguous rows per head)
    for (int i = tid; i < 12*4*200; i += 256) {
        const int h = i / 800, rem = i - h*800, n = rem / 200, m = rem - n*200;
        float vv = 0.f;
        if (m < N_ && n0 + n < N_)
            vv = SC[(((size_t)(b*12 + h))*N_ + n0 + n)*N_ + m];
        sbuf[h][n][m] = vv;
    }
    __syncthreads();
    // phase2: conv_l, in place
    for (int p = tid; p < 4*N_; p += 256) {
        const int n = p / N_, m = p - n*N_;
        float in[12];
        #pragma unroll
        for (int h = 0; h < 12; h++) in[h] = sbuf[h][n][m];
        #pragma unroll
        for (int o = 0; o < 12; o++) {
            float s = 0.f;
            #pragma unroll
            for (int h = 0; h < 12; h++) s += wls[o*12 + h] * in[h];
            sbuf[o][n][m] = s;
        }
    }
    __syncthreads();
    // phase3: row softmax, write probs, keep P in place
    const int w = tid >> 6, l = tid & 63;
    for (int rid = w; rid < 48; rid += 4) {
        const int o = rid >> 2, n = rid & 3;
        const int ng = n0 + n;
        float vv[4];
        float mx = -1e30f;
        #pragma unroll
        for (int c = 0; c < 4; c++) {
            const int m = l + 64*c;
            vv[c] = (m < N_) ? sbuf[o][n][m] : -1e30f;
            mx = fmaxf(mx, vv[c]);
        }
        #pragma unroll
        for (int off = 32; off; off >>= 1) mx = fmaxf(mx, __shfl_xor(mx, off));
        float s = 0.f;
        #pragma unroll
        for (int c = 0; c < 4; c++) {
            const int m = l + 64*c;
            if (m < N_) { vv[c] = __expf(vv[c] - mx); s += vv[c]; }
        }
        #pragma unroll
        for (int off = 32; off; off >>= 1) s += __shfl_xor(s, off);
        const float inv = 1.f / s;
        #pragma unroll
        for (int c = 0; c < 4; c++) {
            const int m = l + 64*c;
            if (m < N_) {
                const float pv = vv[c] * inv;
                if (ng < N_)
                    PR[((((size_t)(b*12 + o))*N_ + ng)*N_) + m] = pv;
                sbuf[o][n][m] = pv;
            }
        }
    }
    __syncthreads();
    // phase4: conv_w from in-place P -> aw (bf16, [197][224])
    for (int p = tid; p < 4*N_; p += 256) {
        const int n = p / N_, m = p - n*N_;
        const int ng = n0 + n;
        if (ng >= N_) continue;
        float in[12];
        #pragma unroll
        for (int h = 0; h < 12; h++) in[h] = sbuf[h][n][m];
        #pragma unroll
        for (int o = 0; o < 12; o++) {
            float s = 0.f;
            #pragma unroll
            for (int h = 0; h < 12; h++) s += wws[o*12 + h] * in[h];
            AW[((size_t)(b*12 + o)*N_ + ng)*KP_ + m] = (__bf16)s;
        }
    }
    // zero aw pad cols m in [197,224)
    for (int p = tid; p < 12*4*(KP_-N_); p += 256) {
        const int o = p / (4*(KP_-N_));
        const int rem = p - o*(4*(KP_-N_));
        const int n = rem / (KP_-N_);
        const int m = N_ + rem - n*(KP_-N_);
        const int ng = n0 + n;
        if (ng < N_)
            AW[((size_t)(b*12 + o)*N_ + ng)*KP_ + m] = (__bf16)0.f;
    }
}

// ---------------------------------------------------------------------------
// av: OP[b,n,h*64+d] = sum_m AW[bh,n,m] * V[bh,m,d].
// Two blocks per bh (768 blocks, 3/CU). vT comes pre-transposed+swizzled from
// mfma_qkv -> stage via gl_lds16 (no per-block transpose, no LDS zeroing).
// Swizzled read: 2-way bank aliasing (free) instead of 8-way.
__global__ __launch_bounds__(256) void av_mfma(const __bf16* __restrict__ AW,
        const __bf16* __restrict__ VT, __bf16* __restrict__ OP) {
    __shared__ __bf16 Vt[64*VTS_];   // 32 KB
    const int tid = threadIdx.x;
    const int bh = blockIdx.x >> 1, half = blockIdx.x & 1;
    const int w = tid >> 6, L = tid & 63;
    const __bf16* Vg = VT + (size_t)bh*64*VTS_;
    #pragma unroll
    for (int i = tid; i < 2048; i += 256)        // 2048 x 16B = 32 KB
        gl_lds16(Vg + (size_t)i*8, (char*)Vt + (size_t)i*16);
    __syncthreads();
    const int lm = L & 15, lg = L >> 4;
    const int b = bh / H_, h = bh - b*H_;
    const __bf16* Ab = AW + (size_t)bh*N_*KP_;
    const int rt0 = half ? 7 : 0;
    const int rt1 = half ? 13 : 7;
    for (int rt = rt0 + w; rt < rt1; rt += 4) {
        int ar = rt*16 + lm;
        if (ar >= N_) ar = 0;   // clamp: results for pad rows are discarded
        f32x4 acc[4] = {};
        #pragma unroll
        for (int k0 = 0; k0 < KP_; k0 += 32) {
            const bf16x8 a = *(const bf16x8*)&Ab[(size_t)ar*KP_ + k0 + lg*8];
            #pragma unroll
            for (int ct = 0; ct < 4; ct++) {
                const int dr = ct*16 + lm;
                const int slot = (k0 >> 3) + lg;
                const bf16x8 bf = *(const bf16x8*)
                    &Vt[dr*VTS_ + ((slot ^ (dr & 7)) << 3)];
                acc[ct] = __builtin_amdgcn_mfma_f32_16x16x32_bf16(
                              a, bf, acc[ct], 0, 0, 0);
            }
        }
        const int rbase = rt*16 + lg*4;
        #pragma unroll
        for (int ct = 0; ct < 4; ct++) {
            const int d = ct*16 + lm;
            #pragma unroll
            for (int r = 0; r < 4; r++) {
                const int row = rbase + r;
                if (row < N_)
                    OP[((size_t)(b*N_ + row))*C_ + h*64 + d] = (__bf16)acc[ct][r];
            }
        }
    }
}

// ---------------------------------------------------------------------------
extern "C" void kernel_launch(void* const* d_in, const int* in_sizes, int n_in,
                              void* d_out, int out_size, void* d_ws, size_t ws_size,
                              hipStream_t stream) {
    const float* x      = (const float*)d_in[0];
    const float* w_qkv  = (const float*)d_in[1];
    const float* w_proj = (const float*)d_in[2];
    const float* b_proj = (const float*)d_in[3];
    const float* w_cl   = (const float*)d_in[4];
    const float* w_cw   = (const float*)d_in[5];

    float* out    = (float*)d_out;                    // [B,N,C]
    float* scores = out    + (size_t)M_ * C_;         // [B,H,N,N]
    float* probs  = scores + (size_t)BH_ * NN_;       // [B,H,N,N]
    float* vmap   = probs  + (size_t)BH_ * NN_;       // [B,H,N,N]

    char* base = (char*)d_ws;
    const size_t QS = (size_t)BH_ * N_ * D_;          // elements per q/k/v
    __bf16* q   = (__bf16*)base;                      // 9.68 MB
    __bf16* k   = q + QS;
    __bf16* v   = k + QS;
    __bf16* Xb  = v + QS;                             // [6400,768] 9.8 MB
    __bf16* OPb = Xb;                                 // alias (pad rows stay 0)
    __bf16* Wqt = Xb + (size_t)MPAD_*768;             // [2304,768]
    __bf16* Wpt = Wqt + (size_t)K3_*768;              // [768,768]
    __bf16* aw  = Wpt + (size_t)768*768;              // [B,H,197,224] 33.9 MB
    __bf16* vT  = aw  + (size_t)BH_*N_*KP_;           // [B,H,64,256] 12.6 MB

    // prep grid: 4800 cast + 1728 wqkv-T + 576 wproj-T + 3072 vT-zero
    prep_kernel   <<<10176,         256, 0, stream>>>(x, Xb, w_qkv, Wqt,
                                                      w_proj, Wpt, vT);
    mfma_qkv      <<<dim3(50, 18),  256, 0, stream>>>(Xb, Wqt, q, k, v, vT);
    qkt_vvt       <<<2*BH_,         256, 0, stream>>>(q, k, v, scores, vmap);
    convl_convw   <<<32*50,         256, 0, stream>>>(scores, w_cl, w_cw, probs, aw);
    av_mfma       <<<2*BH_,         256, 0, stream>>>(aw, vT, OPb);
    mfma_proj     <<<dim3(50, 6),   256, 0, stream>>>(OPb, Wpt, b_proj, out);
}

// Round 6
// 388.900 us; speedup vs baseline: 1.0636x; 1.0636x over previous
//
#include <hip/hip_runtime.h>
#include <cmath>

#define B_ 32
#define N_ 197
#define C_ 768
#define H_ 12
#define D_ 64
#define M_ (B_*N_)        // 6304
#define MPAD_ 6400        // padded rows for 128-tiles
#define K3_ (3*C_)        // 2304
#define NN_ (N_*N_)       // 38809
#define BH_ (B_*H_)       // 384
#define NP_ 208           // 13*16 row pad
#define KP_ 224           // 7*32 k pad for av (aw row stride)
#define VTS_ 256          // av LDS V row stride (pow2 so XOR swizzle is bijective)
#define SCALE 0.125f

typedef __bf16 bf16x8 __attribute__((ext_vector_type(8)));
typedef __bf16 bf16x4 __attribute__((ext_vector_type(4)));
typedef float  f32x4  __attribute__((ext_vector_type(4)));
// 4-byte-aligned float4 for stores at (row*197 + m)*4B addresses (not 16B aligned)
typedef float  f32x4u __attribute__((ext_vector_type(4), aligned(4)));

__device__ __forceinline__ void gl_lds16(const void* g, void* l) {
    __builtin_amdgcn_global_load_lds(
        (const __attribute__((address_space(1))) void*)g,
        (__attribute__((address_space(3))) void*)l,
        16, 0, 0);
}

// ---------------------------------------------------------------------------
// cast X [6304,768] f32 -> Xb [6400,768] bf16 (pad rows zeroed)
__global__ __launch_bounds__(256) void cast_x_kernel(const float* __restrict__ X,
        __bf16* __restrict__ Xb) {
    const long long i = ((long long)blockIdx.x * 256 + threadIdx.x) * 4;
    if (i >= (long long)MPAD_ * 768) return;
    bf16x4 o;
    if (i < (long long)M_ * 768) {
        float4 f = *(const float4*)&X[i];
        o.x = (__bf16)f.x; o.y = (__bf16)f.y; o.z = (__bf16)f.z; o.w = (__bf16)f.w;
    } else {
        o.x = o.y = o.z = o.w = (__bf16)0.f;
    }
    *(bf16x4*)&Xb[i] = o;
}

// ---------------------------------------------------------------------------
// transpose-cast W [R,Ccols] f32 -> Wt [Ccols,R] bf16
__global__ __launch_bounds__(256) void transpose_cast(const float* __restrict__ W,
        __bf16* __restrict__ Wt, int R, int Ccols) {
    __shared__ float t[32][33];
    const int c0 = blockIdx.x * 32;
    const int r0 = blockIdx.y * 32;
    const int tx = threadIdx.x & 31, ty = threadIdx.x >> 5;
    #pragma unroll
    for (int i = ty; i < 32; i += 8)
        t[i][tx] = W[(size_t)(r0 + i) * Ccols + c0 + tx];
    __syncthreads();
    #pragma unroll
    for (int i = ty; i < 32; i += 8)
        Wt[(size_t)(c0 + i) * R + r0 + tx] = (__bf16)t[tx][i];
}

// ---------------------------------------------------------------------------
// MFMA GEMM: Xb[M,768] @ Wt[2304,768]^T -> scatter to q,k,v BF16 [B,H,N,D]
__global__ __launch_bounds__(256) void mfma_qkv(const __bf16* __restrict__ Xb,
        const __bf16* __restrict__ Wt, __bf16* __restrict__ q,
        __bf16* __restrict__ k, __bf16* __restrict__ v) {
    __shared__ __bf16 As[128*32];
    __shared__ __bf16 Bs[128*32];
    const int tid = threadIdx.x;
    const int wv = tid >> 6, ln = tid & 63;
    const int R0 = blockIdx.x * 128;
    const int C0 = blockIdx.y * 128;
    const int wm = wv >> 1, wn = wv & 1;
    const int arow = ln >> 2, akg = ln & 3;
    f32x4 acc[4][4] = {};
    for (int k0 = 0; k0 < 768; k0 += 32) {
        __syncthreads();
        #pragma unroll
        for (int s = 0; s < 2; s++) {
            const int seg = wv + s*4;
            const int row = seg*16 + arow;
            gl_lds16(Xb + (size_t)(R0 + row)*768 + k0 + akg*8,
                     (char*)As + seg*1024 + ln*16);
            gl_lds16(Wt + (size_t)(C0 + row)*768 + k0 + akg*8,
                     (char*)Bs + seg*1024 + ln*16);
        }
        __syncthreads();
        bf16x8 af[4], bfr[4];
        #pragma unroll
        for (int t = 0; t < 4; t++) {
            af[t]  = *(const bf16x8*)((const char*)As +
                        (wm*64 + t*16 + (ln & 15))*64 + (ln >> 4)*16);
            bfr[t] = *(const bf16x8*)((const char*)Bs +
                        (wn*64 + t*16 + (ln & 15))*64 + (ln >> 4)*16);
        }
        #pragma unroll
        for (int i = 0; i < 4; i++)
            #pragma unroll
            for (int j = 0; j < 4; j++)
                acc[i][j] = __builtin_amdgcn_mfma_f32_16x16x32_bf16(
                                af[i], bfr[j], acc[i][j], 0, 0, 0);
    }
    const int lr = (ln >> 4) * 4;
    const int lc = ln & 15;
    #pragma unroll
    for (int j = 0; j < 4; j++) {
        const int c = C0 + wn*64 + j*16 + lc;
        const int which = c / 768;
        const int rem = c - which*768;
        const int h = rem >> 6, d = rem & 63;
        __bf16* dst = (which == 0) ? q : ((which == 1) ? k : v);
        #pragma unroll
        for (int i = 0; i < 4; i++) {
            #pragma unroll
            for (int rr = 0; rr < 4; rr++) {
                const int r = R0 + wm*64 + i*16 + lr + rr;
                if (r < M_) {
                    const int bb = r / N_, n = r - bb*N_;
                    dst[(((size_t)(bb*H_ + h))*N_ + n)*64 + d] =
                        (__bf16)acc[i][j][rr];
                }
            }
        }
    }
}

// ---------------------------------------------------------------------------
// MFMA GEMM: out[M,768] = OPb[M,768] @ Wpt[768,768]^T + bias (fp32 out)
__global__ __launch_bounds__(256) void mfma_proj(const __bf16* __restrict__ Ab,
        const __bf16* __restrict__ Wt, const float* __restrict__ bias,
        float* __restrict__ Y) {
    __shared__ __bf16 As[128*32];
    __shared__ __bf16 Bs[128*32];
    const int tid = threadIdx.x;
    const int wv = tid >> 6, ln = tid & 63;
    const int R0 = blockIdx.x * 128;
    const int C0 = blockIdx.y * 128;
    const int wm = wv >> 1, wn = wv & 1;
    const int arow = ln >> 2, akg = ln & 3;
    f32x4 acc[4][4] = {};
    for (int k0 = 0; k0 < 768; k0 += 32) {
        __syncthreads();
        #pragma unroll
        for (int s = 0; s < 2; s++) {
            const int seg = wv + s*4;
            const int row = seg*16 + arow;
            gl_lds16(Ab + (size_t)(R0 + row)*768 + k0 + akg*8,
                     (char*)As + seg*1024 + ln*16);
            gl_lds16(Wt + (size_t)(C0 + row)*768 + k0 + akg*8,
                     (char*)Bs + seg*1024 + ln*16);
        }
        __syncthreads();
        bf16x8 af[4], bfr[4];
        #pragma unroll
        for (int t = 0; t < 4; t++) {
            af[t]  = *(const bf16x8*)((const char*)As +
                        (wm*64 + t*16 + (ln & 15))*64 + (ln >> 4)*16);
            bfr[t] = *(const bf16x8*)((const char*)Bs +
                        (wn*64 + t*16 + (ln & 15))*64 + (ln >> 4)*16);
        }
        #pragma unroll
        for (int i = 0; i < 4; i++)
            #pragma unroll
            for (int j = 0; j < 4; j++)
                acc[i][j] = __builtin_amdgcn_mfma_f32_16x16x32_bf16(
                                af[i], bfr[j], acc[i][j], 0, 0, 0);
    }
    const int lr = (ln >> 4) * 4;
    const int lc = ln & 15;
    #pragma unroll
    for (int j = 0; j < 4; j++) {
        const int c = C0 + wn*64 + j*16 + lc;
        const float bv = bias[c];
        #pragma unroll
        for (int i = 0; i < 4; i++) {
            #pragma unroll
            for (int rr = 0; rr < 4; rr++) {
                const int r = R0 + wm*64 + i*16 + lr + rr;
                if (r < M_) Y[(size_t)r*768 + c] = acc[i][j][rr] + bv;
            }
        }
    }
}

// ---------------------------------------------------------------------------
// Fused dual kernel: blocks [0,384) S = SCALE*Q K^T, rest VM = softmax(SCALE*V V^T).
// LDS XOR-swizzle (16B slot ^= row&7): balances fragment reads across all 32
// banks (was: banks 0-15 at 16 touches, banks 16-31 idle -> 2x LDS rounds).
// QK path: per-wave Q-frags preloaded into registers (4 static nt entries),
// mt loop outer -> K-frag LDS reads drop from 28 to 2 per 26 MFMAs.
// Swapped operands mfma(K,Q): lane owns 4 consecutive m -> float4 stores.
__global__ __launch_bounds__(256) void qkt_vvt(const __bf16* __restrict__ Q,
        const __bf16* __restrict__ Km, const __bf16* __restrict__ V,
        float* __restrict__ S, float* __restrict__ VM) {
    __shared__ __bf16 Al[NP_*64];
    __shared__ __bf16 Bl[NP_*64];
    const int tid = threadIdx.x;
    const int w = tid >> 6, L = tid & 63;
    const int lm = L & 15, lg = L >> 4;
    if (blockIdx.x < BH_) {
        // ----- QK^T path -----
        const int bh = blockIdx.x;
        const __bf16* Qb = Q  + (size_t)bh*N_*D_;
        const __bf16* Kb = Km + (size_t)bh*N_*D_;
        for (int i = tid*8; i < NP_*64; i += 2048) {
            const int row = i >> 6;
            const int di = (i & ~63) | ((((i >> 3) & 7) ^ (row & 7)) << 3);
            bf16x8 z = {};
            *(bf16x8*)&Al[di] = (row < N_) ? *(const bf16x8*)&Qb[i] : z;
            *(bf16x8*)&Bl[di] = (row < N_) ? *(const bf16x8*)&Kb[i] : z;
        }
        __syncthreads();
        // preload this wave's Q fragments (static 4-entry unroll; entry 3 is
        // nt=12 on wave 0, duplicate of entry 0 elsewhere with store masked)
        const bool isw0 = (w == 0);
        int nts[4];
        nts[0] = w; nts[1] = w + 4; nts[2] = w + 8; nts[3] = isw0 ? 12 : w;
        bf16x8 qf0[4], qf1[4];
        #pragma unroll
        for (int t = 0; t < 4; t++) {
            const int qr = nts[t]*16 + lm;
            qf0[t] = *(const bf16x8*)&Al[qr*64 + ((lg ^ (qr & 7)) << 3)];
            qf1[t] = *(const bf16x8*)&Al[qr*64 + (((4 + lg) ^ (qr & 7)) << 3)];
        }
        for (int mt = 0; mt < 13; mt++) {
            const int kr = mt*16 + lm;
            const bf16x8 k0 = *(const bf16x8*)&Bl[kr*64 + ((lg ^ (kr & 7)) << 3)];
            const bf16x8 k1 = *(const bf16x8*)&Bl[kr*64 + (((4 + lg) ^ (kr & 7)) << 3)];
            const int m0 = mt*16 + lg*4;
            #pragma unroll
            for (int t = 0; t < 4; t++) {
                f32x4 acc = {};
                acc = __builtin_amdgcn_mfma_f32_16x16x32_bf16(k0, qf0[t], acc, 0, 0, 0);
                acc = __builtin_amdgcn_mfma_f32_16x16x32_bf16(k1, qf1[t], acc, 0, 0, 0);
                const int n = nts[t]*16 + lm;
                if ((t < 3 || isw0) && n < N_) {
                    float* Srow = S + ((size_t)bh*N_ + n)*N_;
                    if (m0 + 3 < N_) {
                        f32x4 st;
                        #pragma unroll
                        for (int r = 0; r < 4; r++) st[r] = acc[r] * SCALE;
                        *(f32x4u*)&Srow[m0] = st;
                    } else {
                        #pragma unroll
                        for (int r = 0; r < 4; r++)
                            if (m0 + r < N_) Srow[m0 + r] = acc[r] * SCALE;
                    }
                }
            }
        }
    } else {
        // ----- softmax(V V^T) path -----
        const int bh = blockIdx.x - BH_;
        const __bf16* Vb = V + (size_t)bh*N_*D_;
        for (int i = tid*8; i < NP_*64; i += 2048) {
            const int row = i >> 6;
            const int di = (i & ~63) | ((((i >> 3) & 7) ^ (row & 7)) << 3);
            bf16x8 z = {};
            *(bf16x8*)&Al[di] = (row < N_) ? *(const bf16x8*)&Vb[i] : z;
        }
        __syncthreads();
        for (int nt = w; nt < 13; nt += 4) {
            const int qr = nt*16 + lm;
            const bf16x8 q0 = *(const bf16x8*)&Al[qr*64 + ((lg ^ (qr & 7)) << 3)];
            const bf16x8 q1 = *(const bf16x8*)&Al[qr*64 + (((4 + lg) ^ (qr & 7)) << 3)];
            f32x4 acc[13];
            for (int mt = 0; mt < 13; mt++) {
                const int kr = mt*16 + lm;
                const bf16x8 a0 = *(const bf16x8*)&Al[kr*64 + ((lg ^ (kr & 7)) << 3)];
                const bf16x8 a1 = *(const bf16x8*)&Al[kr*64 + (((4 + lg) ^ (kr & 7)) << 3)];
                f32x4 a = {};
                a = __builtin_amdgcn_mfma_f32_16x16x32_bf16(a0, q0, a, 0, 0, 0);
                a = __builtin_amdgcn_mfma_f32_16x16x32_bf16(a1, q1, a, 0, 0, 0);
                acc[mt] = a;
            }
            // scale; mask invalid m in last tile (m = 192 + lg*4 + r)
            #pragma unroll
            for (int mt = 0; mt < 13; mt++)
                #pragma unroll
                for (int r = 0; r < 4; r++) acc[mt][r] *= SCALE;
            #pragma unroll
            for (int r = 0; r < 4; r++)
                if (192 + lg*4 + r >= N_) acc[12][r] = -1e30f;
            float mx = -1e30f;
            #pragma unroll
            for (int mt = 0; mt < 13; mt++)
                #pragma unroll
                for (int r = 0; r < 4; r++) mx = fmaxf(mx, acc[mt][r]);
            mx = fmaxf(mx, __shfl_xor(mx, 16));
            mx = fmaxf(mx, __shfl_xor(mx, 32));
            float sm = 0.f;
            #pragma unroll
            for (int mt = 0; mt < 13; mt++)
                #pragma unroll
                for (int r = 0; r < 4; r++) {
                    const float e = __expf(acc[mt][r] - mx);
                    acc[mt][r] = e;
                    sm += e;
                }
            sm += __shfl_xor(sm, 16);
            sm += __shfl_xor(sm, 32);
            const float inv = 1.f / sm;
            const int n = qr;
            if (n < N_) {
                float* Vrow = VM + ((size_t)bh*N_ + n)*N_;
                #pragma unroll
                for (int mt = 0; mt < 12; mt++) {
                    f32x4 st;
                    #pragma unroll
                    for (int r = 0; r < 4; r++) st[r] = acc[mt][r] * inv;
                    *(f32x4u*)&Vrow[mt*16 + lg*4] = st;
                }
                #pragma unroll
                for (int r = 0; r < 4; r++) {
                    const int m = 192 + lg*4 + r;
                    if (m < N_) Vrow[m] = acc[12][r] * inv;
                }
            }
        }
    }
}

// ---------------------------------------------------------------------------
// Fused: probs = softmax(conv_l(scores)) AND attn_w = conv_w(probs).
// One block per (b,n) — the round-1 (383us-verified) version.
__global__ __launch_bounds__(256) void convl_convw(const float* __restrict__ SC,
        const float* __restrict__ wl, const float* __restrict__ ww,
        float* __restrict__ PR, __bf16* __restrict__ AW) {
    __shared__ float raw[12*200];     // scores, then reused for probs
    __shared__ float mixed[12*200];
    __shared__ float wls[144];
    __shared__ float wws[144];
    const int tid = threadIdx.x;
    const int b = blockIdx.x / N_;
    const int n = blockIdx.x - b * N_;
    if (tid < 144) { wls[tid] = wl[tid]; wws[tid] = ww[tid]; }
    for (int i = tid; i < 12*N_; i += 256) {
        int h = i / N_, m = i - h*N_;
        raw[h*200 + m] = SC[(((size_t)(b*12 + h))*N_ + n)*N_ + m];
    }
    __syncthreads();
    for (int i = tid; i < 12*N_; i += 256) {
        int o = i / N_, m = i - o*N_;
        float s = 0.f;
        #pragma unroll
        for (int h = 0; h < 12; h++) s += wls[o*12 + h] * raw[h*200 + m];
        mixed[o*200 + m] = s;
    }
    __syncthreads();
    const int w = tid >> 6, l = tid & 63;
    for (int j = 0; j < 3; j++) {
        const int o = w*3 + j;
        float vv[4];
        float mx = -1e30f;
        #pragma unroll
        for (int c = 0; c < 4; c++) {
            int m = l + 64*c;
            vv[c] = (m < N_) ? mixed[o*200 + m] : -1e30f;
            mx = fmaxf(mx, vv[c]);
        }
        #pragma unroll
        for (int off = 32; off; off >>= 1) mx = fmaxf(mx, __shfl_xor(mx, off));
        float s = 0.f;
        #pragma unroll
        for (int c = 0; c < 4; c++) {
            int m = l + 64*c;
            if (m < N_) { vv[c] = __expf(vv[c] - mx); s += vv[c]; }
        }
        #pragma unroll
        for (int off = 32; off; off >>= 1) s += __shfl_xor(s, off);
        const float inv = 1.f / s;
        float* Prow = PR + (((size_t)(b*12 + o))*N_ + n)*N_;
        #pragma unroll
        for (int c = 0; c < 4; c++) {
            int m = l + 64*c;
            if (m < N_) {
                const float p = vv[c] * inv;
                Prow[m] = p;
                raw[o*200 + m] = p;   // keep probs resident for conv_w
            }
        }
    }
    __syncthreads();
    // conv_w from LDS probs -> aw (bf16, padded [197][224], pads zeroed)
    for (int i = tid; i < 12*KP_; i += 256) {
        int o = i / KP_, m = i - o*KP_;
        float s = 0.f;
        if (m < N_) {
            #pragma unroll
            for (int h = 0; h < 12; h++) s += wws[o*12 + h] * raw[h*200 + m];
        }
        AW[((size_t)(b*12 + o)*N_ + n)*KP_ + m] = (__bf16)s;
    }
}

// ---------------------------------------------------------------------------
// av: OP[b,n,h*64+d] = sum_m AW[bh,n,m] * V[bh,m,d]. One block per bh.
// Vt restrided to 256 elems (512B, pow2) + XOR-swizzled 16B slots:
// fragment reads were 8-way bank-imbalanced (448B stride = 2 bank phases),
// now balanced across all 32 banks. Transpose-write uses the same swizzle.
__global__ __launch_bounds__(256) void av_mfma(const __bf16* __restrict__ AW,
        const __bf16* __restrict__ V, __bf16* __restrict__ OP) {
    __shared__ __bf16 Vt[64*VTS_];   // 32 KB
    const int tid = threadIdx.x, bh = blockIdx.x;
    const int w = tid >> 6, L = tid & 63;
    for (int i = tid*8; i < 64*VTS_; i += 2048) {
        bf16x8 z = {};
        *(bf16x8*)&Vt[i] = z;
    }
    __syncthreads();
    const __bf16* Vb = V + (size_t)bh*N_*D_;
    for (int i = tid*8; i < N_*D_; i += 2048) {
        const int row = i >> 6, col = i & 63;
        const bf16x8 vv = *(const bf16x8*)&Vb[i];
        #pragma unroll
        for (int j = 0; j < 8; j++) {
            const int d = col + j;
            Vt[d*VTS_ + ((((row >> 3) ^ (d & 7)) << 3) | (row & 7))] = vv[j];
        }
    }
    __syncthreads();
    const int lm = L & 15, lg = L >> 4;
    const int b = bh / H_, h = bh - b*H_;
    const __bf16* Ab = AW + (size_t)bh*N_*KP_;
    for (int rt = w; rt < 13; rt += 4) {
        int ar = rt*16 + lm;
        if (ar >= N_) ar = 0;   // clamp: results for pad rows are discarded
        f32x4 acc[4] = {};
        #pragma unroll
        for (int k0 = 0; k0 < KP_; k0 += 32) {
            const bf16x8 a = *(const bf16x8*)&Ab[(size_t)ar*KP_ + k0 + lg*8];
            #pragma unroll
            for (int ct = 0; ct < 4; ct++) {
                const int dr = ct*16 + lm;
                const bf16x8 bf = *(const bf16x8*)
                    &Vt[dr*VTS_ + ((((k0 >> 3) + lg) ^ (lm & 7)) << 3)];
                acc[ct] = __builtin_amdgcn_mfma_f32_16x16x32_bf16(
                              a, bf, acc[ct], 0, 0, 0);
            }
        }
        const int rbase = rt*16 + lg*4;
        #pragma unroll
        for (int ct = 0; ct < 4; ct++) {
            const int d = ct*16 + lm;
            #pragma unroll
            for (int r = 0; r < 4; r++) {
                const int row = rbase + r;
                if (row < N_)
                    OP[((size_t)(b*N_ + row))*C_ + h*64 + d] = (__bf16)acc[ct][r];
            }
        }
    }
}

// ---------------------------------------------------------------------------
extern "C" void kernel_launch(void* const* d_in, const int* in_sizes, int n_in,
                              void* d_out, int out_size, void* d_ws, size_t ws_size,
                              hipStream_t stream) {
    const float* x      = (const float*)d_in[0];
    const float* w_qkv  = (const float*)d_in[1];
    const float* w_proj = (const float*)d_in[2];
    const float* b_proj = (const float*)d_in[3];
    const float* w_cl   = (const float*)d_in[4];
    const float* w_cw   = (const float*)d_in[5];

    float* out    = (float*)d_out;                    // [B,N,C]
    float* scores = out    + (size_t)M_ * C_;         // [B,H,N,N]
    float* probs  = scores + (size_t)BH_ * NN_;       // [B,H,N,N]
    float* vmap   = probs  + (size_t)BH_ * NN_;       // [B,H,N,N]

    char* base = (char*)d_ws;
    const size_t QS = (size_t)BH_ * N_ * D_;          // elements per q/k/v
    __bf16* q   = (__bf16*)base;                      // 9.68 MB
    __bf16* k   = q + QS;
    __bf16* v   = k + QS;
    __bf16* Xb  = v + QS;                             // [6400,768] 9.8 MB
    __bf16* OPb = Xb;                                 // alias (pad rows stay 0)
    __bf16* Wqt = Xb + (size_t)MPAD_*768;             // [2304,768]
    __bf16* Wpt = Wqt + (size_t)K3_*768;              // [768,768]
    __bf16* aw  = Wpt + (size_t)768*768;              // [B,H,197,224] 33.9 MB

    cast_x_kernel <<<(MPAD_*768/4 + 255)/256, 256, 0, stream>>>(x, Xb);
    transpose_cast<<<dim3(72, 24),  256, 0, stream>>>(w_qkv,  Wqt, 768, K3_);
    transpose_cast<<<dim3(24, 24),  256, 0, stream>>>(w_proj, Wpt, 768, 768);

    mfma_qkv      <<<dim3(50, 18),  256, 0, stream>>>(Xb, Wqt, q, k, v);
    qkt_vvt       <<<2*BH_,         256, 0, stream>>>(q, k, v, scores, vmap);
    convl_convw   <<<M_,            256, 0, stream>>>(scores, w_cl, w_cw, probs, aw);
    av_mfma       <<<BH_,           256, 0, stream>>>(aw, v, OPb);
    mfma_proj     <<<dim3(50, 6),   256, 0, stream>>>(OPb, Wpt, b_proj, out);
}

// Round 7
// 370.754 us; speedup vs baseline: 1.1156x; 1.0489x over previous
//
#include <hip/hip_runtime.h>
#include <cmath>

#define B_ 32
#define N_ 197
#define C_ 768
#define H_ 12
#define D_ 64
#define M_ (B_*N_)        // 6304
#define MPAD_ 6400        // padded rows for 128-tiles
#define K3_ (3*C_)        // 2304
#define NN_ (N_*N_)       // 38809
#define BH_ (B_*H_)       // 384
#define NP_ 208           // 13*16 row pad
#define KP_ 224           // 7*32 k pad for av (aw row stride)
#define VTS_ 256          // av LDS V row stride (pow2 so XOR swizzle is bijective)
#define SCALE 0.125f

typedef __bf16 bf16x8 __attribute__((ext_vector_type(8)));
typedef __bf16 bf16x4 __attribute__((ext_vector_type(4)));
typedef float  f32x4  __attribute__((ext_vector_type(4)));
// 4-byte-aligned float4 for stores at (row*197 + m)*4B addresses (not 16B aligned)
typedef float  f32x4u __attribute__((ext_vector_type(4), aligned(4)));

__device__ __forceinline__ void gl_lds16(const void* g, void* l) {
    __builtin_amdgcn_global_load_lds(
        (const __attribute__((address_space(1))) void*)g,
        (__attribute__((address_space(3))) void*)l,
        16, 0, 0);
}

// ---------------------------------------------------------------------------
// cast X [6304,768] f32 -> Xb [6400,768] bf16 (pad rows zeroed)
__global__ __launch_bounds__(256) void cast_x_kernel(const float* __restrict__ X,
        __bf16* __restrict__ Xb) {
    const long long i = ((long long)blockIdx.x * 256 + threadIdx.x) * 4;
    if (i >= (long long)MPAD_ * 768) return;
    bf16x4 o;
    if (i < (long long)M_ * 768) {
        float4 f = *(const float4*)&X[i];
        o.x = (__bf16)f.x; o.y = (__bf16)f.y; o.z = (__bf16)f.z; o.w = (__bf16)f.w;
    } else {
        o.x = o.y = o.z = o.w = (__bf16)0.f;
    }
    *(bf16x4*)&Xb[i] = o;
}

// ---------------------------------------------------------------------------
// transpose-cast W [R,Ccols] f32 -> Wt [Ccols,R] bf16
__global__ __launch_bounds__(256) void transpose_cast(const float* __restrict__ W,
        __bf16* __restrict__ Wt, int R, int Ccols) {
    __shared__ float t[32][33];
    const int c0 = blockIdx.x * 32;
    const int r0 = blockIdx.y * 32;
    const int tx = threadIdx.x & 31, ty = threadIdx.x >> 5;
    #pragma unroll
    for (int i = ty; i < 32; i += 8)
        t[i][tx] = W[(size_t)(r0 + i) * Ccols + c0 + tx];
    __syncthreads();
    #pragma unroll
    for (int i = ty; i < 32; i += 8)
        Wt[(size_t)(c0 + i) * R + r0 + tx] = (__bf16)t[tx][i];
}

// ---------------------------------------------------------------------------
// MFMA GEMM: Xb[M,768] @ Wt[2304,768]^T -> scatter to q,k,v BF16 [B,H,N,D].
// Double-buffered single-barrier pipeline (T3-minimum): stage(t+1) issued
// AFTER the barrier, compute(t) from the other buffer -> staging latency
// hides under MFMA; one barrier per K-step instead of two.
__global__ __launch_bounds__(256) void mfma_qkv(const __bf16* __restrict__ Xb,
        const __bf16* __restrict__ Wt, __bf16* __restrict__ q,
        __bf16* __restrict__ k, __bf16* __restrict__ v) {
    __shared__ __bf16 As[2][128*32];
    __shared__ __bf16 Bs[2][128*32];
    const int tid = threadIdx.x;
    const int wv = tid >> 6, ln = tid & 63;
    const int R0 = blockIdx.x * 128;
    const int C0 = blockIdx.y * 128;
    const int wm = wv >> 1, wn = wv & 1;
    const int arow = ln >> 2, akg = ln & 3;
    f32x4 acc[4][4] = {};
    // prologue: stage tile 0 into buffer 0
    #pragma unroll
    for (int s = 0; s < 2; s++) {
        const int seg = wv + s*4;
        const int row = seg*16 + arow;
        gl_lds16(Xb + (size_t)(R0 + row)*768 + akg*8,
                 (char*)As[0] + seg*1024 + ln*16);
        gl_lds16(Wt + (size_t)(C0 + row)*768 + akg*8,
                 (char*)Bs[0] + seg*1024 + ln*16);
    }
    for (int t = 0; t < 24; t++) {
        const int cur = t & 1;
        // tile t's loads are the only outstanding VMEM -> drain, publish
        asm volatile("s_waitcnt vmcnt(0)" ::: "memory");
        __syncthreads();
        if (t < 23) {   // stage tile t+1 into the other buffer (stays in
            const int k0 = (t + 1) * 32;                // flight across MFMA)
            #pragma unroll
            for (int s = 0; s < 2; s++) {
                const int seg = wv + s*4;
                const int row = seg*16 + arow;
                gl_lds16(Xb + (size_t)(R0 + row)*768 + k0 + akg*8,
                         (char*)As[cur^1] + seg*1024 + ln*16);
                gl_lds16(Wt + (size_t)(C0 + row)*768 + k0 + akg*8,
                         (char*)Bs[cur^1] + seg*1024 + ln*16);
            }
        }
        bf16x8 af[4], bfr[4];
        #pragma unroll
        for (int f = 0; f < 4; f++) {
            af[f]  = *(const bf16x8*)((const char*)As[cur] +
                        (wm*64 + f*16 + (ln & 15))*64 + (ln >> 4)*16);
            bfr[f] = *(const bf16x8*)((const char*)Bs[cur] +
                        (wn*64 + f*16 + (ln & 15))*64 + (ln >> 4)*16);
        }
        #pragma unroll
        for (int i = 0; i < 4; i++)
            #pragma unroll
            for (int j = 0; j < 4; j++)
                acc[i][j] = __builtin_amdgcn_mfma_f32_16x16x32_bf16(
                                af[i], bfr[j], acc[i][j], 0, 0, 0);
    }
    const int lr = (ln >> 4) * 4;
    const int lc = ln & 15;
    #pragma unroll
    for (int j = 0; j < 4; j++) {
        const int c = C0 + wn*64 + j*16 + lc;
        const int which = c / 768;
        const int rem = c - which*768;
        const int h = rem >> 6, d = rem & 63;
        __bf16* dst = (which == 0) ? q : ((which == 1) ? k : v);
        #pragma unroll
        for (int i = 0; i < 4; i++) {
            #pragma unroll
            for (int rr = 0; rr < 4; rr++) {
                const int r = R0 + wm*64 + i*16 + lr + rr;
                if (r < M_) {
                    const int bb = r / N_, n = r - bb*N_;
                    dst[(((size_t)(bb*H_ + h))*N_ + n)*64 + d] =
                        (__bf16)acc[i][j][rr];
                }
            }
        }
    }
}

// ---------------------------------------------------------------------------
// MFMA GEMM: out[M,768] = OPb[M,768] @ Wpt[768,768]^T + bias (fp32 out).
// Same double-buffered single-barrier pipeline as mfma_qkv.
__global__ __launch_bounds__(256) void mfma_proj(const __bf16* __restrict__ Ab,
        const __bf16* __restrict__ Wt, const float* __restrict__ bias,
        float* __restrict__ Y) {
    __shared__ __bf16 As[2][128*32];
    __shared__ __bf16 Bs[2][128*32];
    const int tid = threadIdx.x;
    const int wv = tid >> 6, ln = tid & 63;
    const int R0 = blockIdx.x * 128;
    const int C0 = blockIdx.y * 128;
    const int wm = wv >> 1, wn = wv & 1;
    const int arow = ln >> 2, akg = ln & 3;
    f32x4 acc[4][4] = {};
    #pragma unroll
    for (int s = 0; s < 2; s++) {
        const int seg = wv + s*4;
        const int row = seg*16 + arow;
        gl_lds16(Ab + (size_t)(R0 + row)*768 + akg*8,
                 (char*)As[0] + seg*1024 + ln*16);
        gl_lds16(Wt + (size_t)(C0 + row)*768 + akg*8,
                 (char*)Bs[0] + seg*1024 + ln*16);
    }
    for (int t = 0; t < 24; t++) {
        const int cur = t & 1;
        asm volatile("s_waitcnt vmcnt(0)" ::: "memory");
        __syncthreads();
        if (t < 23) {
            const int k0 = (t + 1) * 32;
            #pragma unroll
            for (int s = 0; s < 2; s++) {
                const int seg = wv + s*4;
                const int row = seg*16 + arow;
                gl_lds16(Ab + (size_t)(R0 + row)*768 + k0 + akg*8,
                         (char*)As[cur^1] + seg*1024 + ln*16);
                gl_lds16(Wt + (size_t)(C0 + row)*768 + k0 + akg*8,
                         (char*)Bs[cur^1] + seg*1024 + ln*16);
            }
        }
        bf16x8 af[4], bfr[4];
        #pragma unroll
        for (int f = 0; f < 4; f++) {
            af[f]  = *(const bf16x8*)((const char*)As[cur] +
                        (wm*64 + f*16 + (ln & 15))*64 + (ln >> 4)*16);
            bfr[f] = *(const bf16x8*)((const char*)Bs[cur] +
                        (wn*64 + f*16 + (ln & 15))*64 + (ln >> 4)*16);
        }
        #pragma unroll
        for (int i = 0; i < 4; i++)
            #pragma unroll
            for (int j = 0; j < 4; j++)
                acc[i][j] = __builtin_amdgcn_mfma_f32_16x16x32_bf16(
                                af[i], bfr[j], acc[i][j], 0, 0, 0);
    }
    const int lr = (ln >> 4) * 4;
    const int lc = ln & 15;
    #pragma unroll
    for (int j = 0; j < 4; j++) {
        const int c = C0 + wn*64 + j*16 + lc;
        const float bv = bias[c];
        #pragma unroll
        for (int i = 0; i < 4; i++) {
            #pragma unroll
            for (int rr = 0; rr < 4; rr++) {
                const int r = R0 + wm*64 + i*16 + lr + rr;
                if (r < M_) Y[(size_t)r*768 + c] = acc[i][j][rr] + bv;
            }
        }
    }
}

// ---------------------------------------------------------------------------
// Fused dual kernel: blocks [0,384) S = SCALE*Q K^T, rest VM = softmax(SCALE*V V^T).
// LDS XOR-swizzle (16B slot ^= row&7) balances banks; QK path preloads the
// wave's Q-frags in registers; swapped operands -> float4 stores.
__global__ __launch_bounds__(256) void qkt_vvt(const __bf16* __restrict__ Q,
        const __bf16* __restrict__ Km, const __bf16* __restrict__ V,
        float* __restrict__ S, float* __restrict__ VM) {
    __shared__ __bf16 Al[NP_*64];
    __shared__ __bf16 Bl[NP_*64];
    const int tid = threadIdx.x;
    const int w = tid >> 6, L = tid & 63;
    const int lm = L & 15, lg = L >> 4;
    if (blockIdx.x < BH_) {
        // ----- QK^T path -----
        const int bh = blockIdx.x;
        const __bf16* Qb = Q  + (size_t)bh*N_*D_;
        const __bf16* Kb = Km + (size_t)bh*N_*D_;
        for (int i = tid*8; i < NP_*64; i += 2048) {
            const int row = i >> 6;
            const int di = (i & ~63) | ((((i >> 3) & 7) ^ (row & 7)) << 3);
            bf16x8 z = {};
            *(bf16x8*)&Al[di] = (row < N_) ? *(const bf16x8*)&Qb[i] : z;
            *(bf16x8*)&Bl[di] = (row < N_) ? *(const bf16x8*)&Kb[i] : z;
        }
        __syncthreads();
        // preload this wave's Q fragments (static 4-entry unroll; entry 3 is
        // nt=12 on wave 0, duplicate of entry 0 elsewhere with store masked)
        const bool isw0 = (w == 0);
        int nts[4];
        nts[0] = w; nts[1] = w + 4; nts[2] = w + 8; nts[3] = isw0 ? 12 : w;
        bf16x8 qf0[4], qf1[4];
        #pragma unroll
        for (int t = 0; t < 4; t++) {
            const int qr = nts[t]*16 + lm;
            qf0[t] = *(const bf16x8*)&Al[qr*64 + ((lg ^ (qr & 7)) << 3)];
            qf1[t] = *(const bf16x8*)&Al[qr*64 + (((4 + lg) ^ (qr & 7)) << 3)];
        }
        for (int mt = 0; mt < 13; mt++) {
            const int kr = mt*16 + lm;
            const bf16x8 k0 = *(const bf16x8*)&Bl[kr*64 + ((lg ^ (kr & 7)) << 3)];
            const bf16x8 k1 = *(const bf16x8*)&Bl[kr*64 + (((4 + lg) ^ (kr & 7)) << 3)];
            const int m0 = mt*16 + lg*4;
            #pragma unroll
            for (int t = 0; t < 4; t++) {
                f32x4 acc = {};
                acc = __builtin_amdgcn_mfma_f32_16x16x32_bf16(k0, qf0[t], acc, 0, 0, 0);
                acc = __builtin_amdgcn_mfma_f32_16x16x32_bf16(k1, qf1[t], acc, 0, 0, 0);
                const int n = nts[t]*16 + lm;
                if ((t < 3 || isw0) && n < N_) {
                    float* Srow = S + ((size_t)bh*N_ + n)*N_;
                    if (m0 + 3 < N_) {
                        f32x4 st;
                        #pragma unroll
                        for (int r = 0; r < 4; r++) st[r] = acc[r] * SCALE;
                        *(f32x4u*)&Srow[m0] = st;
                    } else {
                        #pragma unroll
                        for (int r = 0; r < 4; r++)
                            if (m0 + r < N_) Srow[m0 + r] = acc[r] * SCALE;
                    }
                }
            }
        }
    } else {
        // ----- softmax(V V^T) path -----
        const int bh = blockIdx.x - BH_;
        const __bf16* Vb = V + (size_t)bh*N_*D_;
        for (int i = tid*8; i < NP_*64; i += 2048) {
            const int row = i >> 6;
            const int di = (i & ~63) | ((((i >> 3) & 7) ^ (row & 7)) << 3);
            bf16x8 z = {};
            *(bf16x8*)&Al[di] = (row < N_) ? *(const bf16x8*)&Vb[i] : z;
        }
        __syncthreads();
        for (int nt = w; nt < 13; nt += 4) {
            const int qr = nt*16 + lm;
            const bf16x8 q0 = *(const bf16x8*)&Al[qr*64 + ((lg ^ (qr & 7)) << 3)];
            const bf16x8 q1 = *(const bf16x8*)&Al[qr*64 + (((4 + lg) ^ (qr & 7)) << 3)];
            f32x4 acc[13];
            for (int mt = 0; mt < 13; mt++) {
                const int kr = mt*16 + lm;
                const bf16x8 a0 = *(const bf16x8*)&Al[kr*64 + ((lg ^ (kr & 7)) << 3)];
                const bf16x8 a1 = *(const bf16x8*)&Al[kr*64 + (((4 + lg) ^ (kr & 7)) << 3)];
                f32x4 a = {};
                a = __builtin_amdgcn_mfma_f32_16x16x32_bf16(a0, q0, a, 0, 0, 0);
                a = __builtin_amdgcn_mfma_f32_16x16x32_bf16(a1, q1, a, 0, 0, 0);
                acc[mt] = a;
            }
            // scale; mask invalid m in last tile (m = 192 + lg*4 + r)
            #pragma unroll
            for (int mt = 0; mt < 13; mt++)
                #pragma unroll
                for (int r = 0; r < 4; r++) acc[mt][r] *= SCALE;
            #pragma unroll
            for (int r = 0; r < 4; r++)
                if (192 + lg*4 + r >= N_) acc[12][r] = -1e30f;
            float mx = -1e30f;
            #pragma unroll
            for (int mt = 0; mt < 13; mt++)
                #pragma unroll
                for (int r = 0; r < 4; r++) mx = fmaxf(mx, acc[mt][r]);
            mx = fmaxf(mx, __shfl_xor(mx, 16));
            mx = fmaxf(mx, __shfl_xor(mx, 32));
            float sm = 0.f;
            #pragma unroll
            for (int mt = 0; mt < 13; mt++)
                #pragma unroll
                for (int r = 0; r < 4; r++) {
                    const float e = __expf(acc[mt][r] - mx);
                    acc[mt][r] = e;
                    sm += e;
                }
            sm += __shfl_xor(sm, 16);
            sm += __shfl_xor(sm, 32);
            const float inv = 1.f / sm;
            const int n = qr;
            if (n < N_) {
                float* Vrow = VM + ((size_t)bh*N_ + n)*N_;
                #pragma unroll
                for (int mt = 0; mt < 12; mt++) {
                    f32x4 st;
                    #pragma unroll
                    for (int r = 0; r < 4; r++) st[r] = acc[mt][r] * inv;
                    *(f32x4u*)&Vrow[mt*16 + lg*4] = st;
                }
                #pragma unroll
                for (int r = 0; r < 4; r++) {
                    const int m = 192 + lg*4 + r;
                    if (m < N_) Vrow[m] = acc[12][r] * inv;
                }
            }
        }
    }
}

// ---------------------------------------------------------------------------
// Fused: probs = softmax(conv_l(scores)) AND attn_w = conv_w(probs).
// One block per (b,n). 12x12 mixes are POSITION-parallel: each thread reads
// the 12 head values for its m once into registers and writes all 12 outputs
// (12x fewer LDS reads + 9x fewer instructions than output-parallel).
__global__ __launch_bounds__(256) void convl_convw(const float* __restrict__ SC,
        const float* __restrict__ wl, const float* __restrict__ ww,
        float* __restrict__ PR, __bf16* __restrict__ AW) {
    __shared__ float raw[12*200];     // scores, then reused for probs
    __shared__ float mixed[12*200];
    __shared__ float wls[144];
    __shared__ float wws[144];
    const int tid = threadIdx.x;
    const int b = blockIdx.x / N_;
    const int n = blockIdx.x - b * N_;
    if (tid < 144) { wls[tid] = wl[tid]; wws[tid] = ww[tid]; }
    for (int i = tid; i < 12*N_; i += 256) {
        int h = i / N_, m = i - h*N_;
        raw[h*200 + m] = SC[(((size_t)(b*12 + h))*N_ + n)*N_ + m];
    }
    __syncthreads();
    // conv_l: position-parallel
    for (int m = tid; m < N_; m += 256) {
        float in[12];
        #pragma unroll
        for (int h = 0; h < 12; h++) in[h] = raw[h*200 + m];
        #pragma unroll
        for (int o = 0; o < 12; o++) {
            float s = 0.f;
            #pragma unroll
            for (int h = 0; h < 12; h++) s += wls[o*12 + h] * in[h];
            mixed[o*200 + m] = s;
        }
    }
    __syncthreads();
    const int w = tid >> 6, l = tid & 63;
    for (int j = 0; j < 3; j++) {
        const int o = w*3 + j;
        float vv[4];
        float mx = -1e30f;
        #pragma unroll
        for (int c = 0; c < 4; c++) {
            int m = l + 64*c;
            vv[c] = (m < N_) ? mixed[o*200 + m] : -1e30f;
            mx = fmaxf(mx, vv[c]);
        }
        #pragma unroll
        for (int off = 32; off; off >>= 1) mx = fmaxf(mx, __shfl_xor(mx, off));
        float s = 0.f;
        #pragma unroll
        for (int c = 0; c < 4; c++) {
            int m = l + 64*c;
            if (m < N_) { vv[c] = __expf(vv[c] - mx); s += vv[c]; }
        }
        #pragma unroll
        for (int off = 32; off; off >>= 1) s += __shfl_xor(s, off);
        const float inv = 1.f / s;
        float* Prow = PR + (((size_t)(b*12 + o))*N_ + n)*N_;
        #pragma unroll
        for (int c = 0; c < 4; c++) {
            int m = l + 64*c;
            if (m < N_) {
                const float p = vv[c] * inv;
                Prow[m] = p;
                raw[o*200 + m] = p;   // keep probs resident for conv_w
            }
        }
    }
    __syncthreads();
    // conv_w: position-parallel from LDS probs -> aw (bf16, [197][224])
    for (int m = tid; m < N_; m += 256) {
        float in[12];
        #pragma unroll
        for (int h = 0; h < 12; h++) in[h] = raw[h*200 + m];
        #pragma unroll
        for (int o = 0; o < 12; o++) {
            float s = 0.f;
            #pragma unroll
            for (int h = 0; h < 12; h++) s += wws[o*12 + h] * in[h];
            AW[((size_t)(b*12 + o)*N_ + n)*KP_ + m] = (__bf16)s;
        }
    }
    // zero aw pad cols m in [197,224)
    for (int i = tid; i < 12*(KP_-N_); i += 256) {
        const int o = i / (KP_-N_);
        const int m = N_ + i - o*(KP_-N_);
        AW[((size_t)(b*12 + o)*N_ + n)*KP_ + m] = (__bf16)0.f;
    }
}

// ---------------------------------------------------------------------------
// av: OP[b,n,h*64+d] = sum_m AW[bh,n,m] * V[bh,m,d]. One block per bh.
// Vt restrided to 256 elems (512B, pow2) + XOR-swizzled 16B slots.
__global__ __launch_bounds__(256) void av_mfma(const __bf16* __restrict__ AW,
        const __bf16* __restrict__ V, __bf16* __restrict__ OP) {
    __shared__ __bf16 Vt[64*VTS_];   // 32 KB
    const int tid = threadIdx.x, bh = blockIdx.x;
    const int w = tid >> 6, L = tid & 63;
    for (int i = tid*8; i < 64*VTS_; i += 2048) {
        bf16x8 z = {};
        *(bf16x8*)&Vt[i] = z;
    }
    __syncthreads();
    const __bf16* Vb = V + (size_t)bh*N_*D_;
    for (int i = tid*8; i < N_*D_; i += 2048) {
        const int row = i >> 6, col = i & 63;
        const bf16x8 vv = *(const bf16x8*)&Vb[i];
        #pragma unroll
        for (int j = 0; j < 8; j++) {
            const int d = col + j;
            Vt[d*VTS_ + ((((row >> 3) ^ (d & 7)) << 3) | (row & 7))] = vv[j];
        }
    }
    __syncthreads();
    const int lm = L & 15, lg = L >> 4;
    const int b = bh / H_, h = bh - b*H_;
    const __bf16* Ab = AW + (size_t)bh*N_*KP_;
    for (int rt = w; rt < 13; rt += 4) {
        int ar = rt*16 + lm;
        if (ar >= N_) ar = 0;   // clamp: results for pad rows are discarded
        f32x4 acc[4] = {};
        #pragma unroll
        for (int k0 = 0; k0 < KP_; k0 += 32) {
            const bf16x8 a = *(const bf16x8*)&Ab[(size_t)ar*KP_ + k0 + lg*8];
            #pragma unroll
            for (int ct = 0; ct < 4; ct++) {
                const int dr = ct*16 + lm;
                const bf16x8 bf = *(const bf16x8*)
                    &Vt[dr*VTS_ + ((((k0 >> 3) + lg) ^ (lm & 7)) << 3)];
                acc[ct] = __builtin_amdgcn_mfma_f32_16x16x32_bf16(
                              a, bf, acc[ct], 0, 0, 0);
            }
        }
        const int rbase = rt*16 + lg*4;
        #pragma unroll
        for (int ct = 0; ct < 4; ct++) {
            const int d = ct*16 + lm;
            #pragma unroll
            for (int r = 0; r < 4; r++) {
                const int row = rbase + r;
                if (row < N_)
                    OP[((size_t)(b*N_ + row))*C_ + h*64 + d] = (__bf16)acc[ct][r];
            }
        }
    }
}

// ---------------------------------------------------------------------------
extern "C" void kernel_launch(void* const* d_in, const int* in_sizes, int n_in,
                              void* d_out, int out_size, void* d_ws, size_t ws_size,
                              hipStream_t stream) {
    const float* x      = (const float*)d_in[0];
    const float* w_qkv  = (const float*)d_in[1];
    const float* w_proj = (const float*)d_in[2];
    const float* b_proj = (const float*)d_in[3];
    const float* w_cl   = (const float*)d_in[4];
    const float* w_cw   = (const float*)d_in[5];

    float* out    = (float*)d_out;                    // [B,N,C]
    float* scores = out    + (size_t)M_ * C_;         // [B,H,N,N]
    float* probs  = scores + (size_t)BH_ * NN_;       // [B,H,N,N]
    float* vmap   = probs  + (size_t)BH_ * NN_;       // [B,H,N,N]

    char* base = (char*)d_ws;
    const size_t QS = (size_t)BH_ * N_ * D_;          // elements per q/k/v
    __bf16* q   = (__bf16*)base;                      // 9.68 MB
    __bf16* k   = q + QS;
    __bf16* v   = k + QS;
    __bf16* Xb  = v + QS;                             // [6400,768] 9.8 MB
    __bf16* OPb = Xb;                                 // alias (pad rows stay 0)
    __bf16* Wqt = Xb + (size_t)MPAD_*768;             // [2304,768]
    __bf16* Wpt = Wqt + (size_t)K3_*768;              // [768,768]
    __bf16* aw  = Wpt + (size_t)768*768;              // [B,H,197,224] 33.9 MB

    cast_x_kernel <<<(MPAD_*768/4 + 255)/256, 256, 0, stream>>>(x, Xb);
    transpose_cast<<<dim3(72, 24),  256, 0, stream>>>(w_qkv,  Wqt, 768, K3_);
    transpose_cast<<<dim3(24, 24),  256, 0, stream>>>(w_proj, Wpt, 768, 768);

    mfma_qkv      <<<dim3(50, 18),  256, 0, stream>>>(Xb, Wqt, q, k, v);
    qkt_vvt       <<<2*BH_,         256, 0, stream>>>(q, k, v, scores, vmap);
    convl_convw   <<<M_,            256, 0, stream>>>(scores, w_cl, w_cw, probs, aw);
    av_mfma       <<<BH_,           256, 0, stream>>>(aw, v, OPb);
    mfma_proj     <<<dim3(50, 6),   256, 0, stream>>>(OPb, Wpt, b_proj, out);
}